// Round 1
// baseline (1496.034 us; speedup 1.0000x reference)
//
#include <hip/hip_runtime.h>

#define N_NODES 100000
#define N_EDGES 1600000
#define FDIM 64
#define NGRAPH 512

// ---------------- degree / dinv ----------------
__global__ void degree_kernel(const int* __restrict__ dst, float* __restrict__ deg, int E) {
    int i = blockIdx.x * blockDim.x + threadIdx.x;
    int stride = gridDim.x * blockDim.x;
    for (; i < E; i += stride) atomicAdd(&deg[dst[i]], 1.0f);
}

__global__ void dinv_kernel(float* __restrict__ deg, int n) {
    int i = blockIdx.x * blockDim.x + threadIdx.x;
    if (i < n) deg[i] = rsqrtf(deg[i] + 1.0f);  // +1 = self loop
}

// ---------------- fp32 GEMM: H = X @ W, X[N][64], W[64][64] ----------------
// block = 256 threads, 64 rows per block. W and transposed-X tile in LDS.
__global__ __launch_bounds__(256) void gemm64(const float* __restrict__ X,
                                              const float* __restrict__ W,
                                              float* __restrict__ Hout, int n) {
    __shared__ float Ws[64 * 64];
    __shared__ float Xs[64 * 65];  // Xs[k][row] at k*65+row (pad kills bank conflicts)
    int t = threadIdx.x;
    int r0 = blockIdx.x * 64;

    #pragma unroll
    for (int k = 0; k < 16; ++k) Ws[t + k * 256] = W[t + k * 256];

    #pragma unroll
    for (int k = 0; k < 16; ++k) {
        int idx = t + k * 256;           // 0..4095
        int row = idx >> 6, col = idx & 63;
        float v = (r0 + row < n) ? X[(size_t)(r0 + row) * FDIM + col] : 0.0f;
        Xs[col * 65 + row] = v;
    }
    __syncthreads();

    int row = t & 63;
    int cg  = (t >> 6) * 16;             // 4 column groups of 16
    float acc[16];
    #pragma unroll
    for (int j = 0; j < 16; ++j) acc[j] = 0.0f;

    for (int k = 0; k < 64; ++k) {
        float xv = Xs[k * 65 + row];
        #pragma unroll
        for (int j = 0; j < 16; ++j) acc[j] += xv * Ws[k * 64 + cg + j];
    }

    if (r0 + row < n) {
        float* o = &Hout[(size_t)(r0 + row) * FDIM + cg];
        #pragma unroll
        for (int j = 0; j < 16; ++j) o[j] = acc[j];
    }
}

// ---------------- edge aggregation: agg[dst] += h[src] * dinv[src]*dinv[dst] ----------------
// one wave per edge (grid-stride), lane = feature
__global__ void agg_kernel(const float* __restrict__ h, const int* __restrict__ src,
                           const int* __restrict__ dst, const float* __restrict__ dinv,
                           float* __restrict__ agg, int E) {
    int wid  = (blockIdx.x * blockDim.x + threadIdx.x) >> 6;
    int lane = threadIdx.x & 63;
    int nw   = (gridDim.x * blockDim.x) >> 6;
    for (int e = wid; e < E; e += nw) {
        int s = src[e], d = dst[e];
        float nrm = dinv[s] * dinv[d];
        float v = h[(size_t)s * FDIM + lane] * nrm;
        atomicAdd(&agg[(size_t)d * FDIM + lane], v);
    }
}

// ---------------- self-loop + bias (+ReLU), in place on agg ----------------
__global__ void fixup_kernel(float* __restrict__ agg, const float* __restrict__ h,
                             const float* __restrict__ dinv, const float* __restrict__ b,
                             int n, int do_relu) {
    int i = blockIdx.x * blockDim.x + threadIdx.x;
    if (i < n * FDIM) {
        int node = i >> 6, j = i & 63;
        float di = dinv[node];
        float v = agg[i] + h[i] * di * di + b[j];
        if (do_relu) v = fmaxf(v, 0.0f);
        agg[i] = v;
    }
}

// ---------------- pooling ----------------
__global__ void pool_kernel(const float* __restrict__ h, const int* __restrict__ batch,
                            float* __restrict__ sums, float* __restrict__ counts, int n) {
    int wid  = (blockIdx.x * blockDim.x + threadIdx.x) >> 6;
    int lane = threadIdx.x & 63;
    if (wid < n) {
        int g = batch[wid];
        atomicAdd(&sums[(size_t)g * FDIM + lane], h[(size_t)wid * FDIM + lane]);
        if (lane == 0) atomicAdd(&counts[g], 1.0f);
    }
}

__global__ void divide_kernel(float* __restrict__ out, const float* __restrict__ counts, int total) {
    int i = blockIdx.x * blockDim.x + threadIdx.x;
    if (i < total) out[i] /= fmaxf(counts[i >> 6], 1.0f);
}

extern "C" void kernel_launch(void* const* d_in, const int* in_sizes, int n_in,
                              void* d_out, int out_size, void* d_ws, size_t ws_size,
                              hipStream_t stream) {
    const float* x    = (const float*)d_in[0];
    const int*   ei   = (const int*)d_in[1];
    const int*   batch= (const int*)d_in[2];
    const float* W1   = (const float*)d_in[3];
    const float* b1   = (const float*)d_in[4];
    const float* W2   = (const float*)d_in[5];
    const float* b2   = (const float*)d_in[6];
    const float* W3   = (const float*)d_in[7];
    const float* b3   = (const float*)d_in[8];
    float* out = (float*)d_out;

    const int N = N_NODES, E = N_EDGES;
    const int* src = ei;
    const int* dst = ei + E;

    // workspace partition (bytes)
    char* ws = (char*)d_ws;
    float* dinv   = (float*)(ws);                        // N floats
    float* hbuf   = (float*)(ws + 400384);               // N*64 floats
    float* aggbuf = (float*)(ws + 400384 + 25600000);    // N*64 floats
    float* counts = (float*)(ws + 400384 + 51200000);    // G floats

    const size_t featBytes = (size_t)N * FDIM * sizeof(float);

    // degree -> dinv
    hipMemsetAsync(dinv, 0, (size_t)N * sizeof(float), stream);
    degree_kernel<<<2048, 256, 0, stream>>>(dst, dinv, E);
    dinv_kernel<<<(N + 255) / 256, 256, 0, stream>>>(dinv, N);

    const int gemmGrid = (N + 63) / 64;
    const int fixGrid  = (N * FDIM + 255) / 256;

    // ---- layer 1 ----
    gemm64<<<gemmGrid, 256, 0, stream>>>(x, W1, hbuf, N);
    hipMemsetAsync(aggbuf, 0, featBytes, stream);
    agg_kernel<<<4096, 256, 0, stream>>>(hbuf, src, dst, dinv, aggbuf, E);
    fixup_kernel<<<fixGrid, 256, 0, stream>>>(aggbuf, hbuf, dinv, b1, N, 1);

    // ---- layer 2 ----
    gemm64<<<gemmGrid, 256, 0, stream>>>(aggbuf, W2, hbuf, N);
    hipMemsetAsync(aggbuf, 0, featBytes, stream);
    agg_kernel<<<4096, 256, 0, stream>>>(hbuf, src, dst, dinv, aggbuf, E);
    fixup_kernel<<<fixGrid, 256, 0, stream>>>(aggbuf, hbuf, dinv, b2, N, 1);

    // ---- layer 3 ----
    gemm64<<<gemmGrid, 256, 0, stream>>>(aggbuf, W3, hbuf, N);
    hipMemsetAsync(aggbuf, 0, featBytes, stream);
    agg_kernel<<<4096, 256, 0, stream>>>(hbuf, src, dst, dinv, aggbuf, E);
    fixup_kernel<<<fixGrid, 256, 0, stream>>>(aggbuf, hbuf, dinv, b3, N, 0);

    // ---- global mean pool ----
    hipMemsetAsync(out, 0, (size_t)NGRAPH * FDIM * sizeof(float), stream);
    hipMemsetAsync(counts, 0, (size_t)NGRAPH * sizeof(float), stream);
    pool_kernel<<<(N * 64 + 255) / 256, 256, 0, stream>>>(aggbuf, batch, out, counts, N);
    divide_kernel<<<(NGRAPH * FDIM + 255) / 256, 256, 0, stream>>>(out, counts, NGRAPH * FDIM);
}

// Round 2
// 692.900 us; speedup vs baseline: 2.1591x; 2.1591x over previous
//
#include <hip/hip_runtime.h>

#define N_NODES 100000
#define N_EDGES 1600000
#define FDIM 64
#define NGRAPH 512

// ================= degree (int) =================
__global__ void degree_kernel(const int* __restrict__ dst, int* __restrict__ deg, int E) {
    int i = blockIdx.x * blockDim.x + threadIdx.x;
    int stride = gridDim.x * blockDim.x;
    for (; i < E; i += stride) atomicAdd(&deg[dst[i]], 1);
}

__global__ void dinv_kernel(const int* __restrict__ deg, float* __restrict__ dinv, int n) {
    int i = blockIdx.x * blockDim.x + threadIdx.x;
    if (i < n) dinv[i] = rsqrtf((float)deg[i] + 1.0f);  // +1 = self loop
}

// ================= 3-kernel exclusive scan over deg -> offsets =================
// scan_block: each 256-thread block scans 1024 elements
__global__ void scan_block(const int* __restrict__ deg, int* __restrict__ excl,
                           int* __restrict__ blocksums, int n) {
    __shared__ int lds[256];
    int t = threadIdx.x;
    int base = blockIdx.x * 1024 + t * 4;
    int v0 = (base     < n) ? deg[base]     : 0;
    int v1 = (base + 1 < n) ? deg[base + 1] : 0;
    int v2 = (base + 2 < n) ? deg[base + 2] : 0;
    int v3 = (base + 3 < n) ? deg[base + 3] : 0;
    int s = v0 + v1 + v2 + v3;
    lds[t] = s;
    __syncthreads();
    for (int off = 1; off < 256; off <<= 1) {
        int x = (t >= off) ? lds[t - off] : 0;
        __syncthreads();
        lds[t] += x;
        __syncthreads();
    }
    int thrExcl = lds[t] - s;
    if (t == 255) blocksums[blockIdx.x] = lds[255];
    if (base     < n) excl[base]     = thrExcl;
    if (base + 1 < n) excl[base + 1] = thrExcl + v0;
    if (base + 2 < n) excl[base + 2] = thrExcl + v0 + v1;
    if (base + 3 < n) excl[base + 3] = thrExcl + v0 + v1 + v2;
}

__global__ void scan_top(int* __restrict__ blocksums, int nb, int* __restrict__ offsets, int n) {
    if (threadIdx.x == 0 && blockIdx.x == 0) {
        int run = 0;
        for (int i = 0; i < nb; ++i) { int v = blocksums[i]; blocksums[i] = run; run += v; }
        offsets[n] = run;  // == E
    }
}

__global__ void scan_add(int* __restrict__ offsets, const int* __restrict__ blocksums, int n) {
    int i = blockIdx.x * blockDim.x + threadIdx.x;
    if (i < n) offsets[i] += blocksums[i >> 10];
}

// ================= CSR scatter =================
__global__ void scatter_kernel(const int* __restrict__ src, const int* __restrict__ dst,
                               const int* __restrict__ offsets, int* __restrict__ cursor,
                               int* __restrict__ csr_src, int E) {
    int i = blockIdx.x * blockDim.x + threadIdx.x;
    int stride = gridDim.x * blockDim.x;
    for (; i < E; i += stride) {
        int d = dst[i];
        int pos = offsets[d] + atomicAdd(&cursor[d], 1);
        csr_src[pos] = src[i];
    }
}

// ================= fp32 GEMM: Hs = (X @ W) * dinv[row] =================
__global__ __launch_bounds__(256) void gemm64(const float* __restrict__ X,
                                              const float* __restrict__ W,
                                              const float* __restrict__ dinv,
                                              float* __restrict__ Hout, int n) {
    __shared__ float Ws[64 * 64];
    __shared__ float Xs[64 * 65];  // Xs[k][row]
    int t = threadIdx.x;
    int r0 = blockIdx.x * 64;

    #pragma unroll
    for (int k = 0; k < 16; ++k) Ws[t + k * 256] = W[t + k * 256];

    #pragma unroll
    for (int k = 0; k < 16; ++k) {
        int idx = t + k * 256;
        int row = idx >> 6, col = idx & 63;
        float v = (r0 + row < n) ? X[(size_t)(r0 + row) * FDIM + col] : 0.0f;
        Xs[col * 65 + row] = v;
    }
    __syncthreads();

    int row = t & 63;
    int cg  = (t >> 6) * 16;
    float acc[16];
    #pragma unroll
    for (int j = 0; j < 16; ++j) acc[j] = 0.0f;

    for (int k = 0; k < 64; ++k) {
        float xv = Xs[k * 65 + row];
        #pragma unroll
        for (int j = 0; j < 16; ++j) acc[j] += xv * Ws[k * 64 + cg + j];
    }

    if (r0 + row < n) {
        float sc = dinv[r0 + row];
        float* o = &Hout[(size_t)(r0 + row) * FDIM + cg];
        #pragma unroll
        for (int j = 0; j < 16; ++j) o[j] = acc[j] * sc;
    }
}

// ================= gather aggregation (fused self-loop + bias + relu) =================
// one wave per dst node, lane = feature. hs is pre-scaled by dinv.
__global__ __launch_bounds__(256) void gather_agg(const float* __restrict__ hs,
                                                  const int* __restrict__ csr_src,
                                                  const int* __restrict__ offsets,
                                                  const float* __restrict__ dinv,
                                                  const float* __restrict__ bias,
                                                  float* __restrict__ outb,
                                                  int n, int do_relu) {
    int node = blockIdx.x * 4 + (threadIdx.x >> 6);
    int lane = threadIdx.x & 63;
    if (node >= n) return;
    int beg = offsets[node], end = offsets[node + 1];
    float acc = 0.0f;
    int k = beg;
    for (; k + 3 < end; k += 4) {
        int s0 = csr_src[k], s1 = csr_src[k + 1], s2 = csr_src[k + 2], s3 = csr_src[k + 3];
        float a0 = hs[(size_t)s0 * FDIM + lane];
        float a1 = hs[(size_t)s1 * FDIM + lane];
        float a2 = hs[(size_t)s2 * FDIM + lane];
        float a3 = hs[(size_t)s3 * FDIM + lane];
        acc += a0 + a1 + a2 + a3;
    }
    for (; k < end; ++k) acc += hs[(size_t)csr_src[k] * FDIM + lane];

    float dd = dinv[node];
    // sum_{s} h[s]*dinv[s]*dinv[d] + h[d]*dinv[d]^2 + b  =  dd*(acc + hs[d]) + b
    float v = dd * (acc + hs[(size_t)node * FDIM + lane]) + bias[lane];
    if (do_relu) v = fmaxf(v, 0.0f);
    outb[(size_t)node * FDIM + lane] = v;
}

// ================= pooling =================
__global__ void pool_kernel(const float* __restrict__ h, const int* __restrict__ batch,
                            float* __restrict__ sums, float* __restrict__ counts, int n) {
    int wid  = (blockIdx.x * blockDim.x + threadIdx.x) >> 6;
    int lane = threadIdx.x & 63;
    if (wid < n) {
        int g = batch[wid];
        atomicAdd(&sums[(size_t)g * FDIM + lane], h[(size_t)wid * FDIM + lane]);
        if (lane == 0) atomicAdd(&counts[g], 1.0f);
    }
}

__global__ void divide_kernel(float* __restrict__ out, const float* __restrict__ counts, int total) {
    int i = blockIdx.x * blockDim.x + threadIdx.x;
    if (i < total) out[i] /= fmaxf(counts[i >> 6], 1.0f);
}

extern "C" void kernel_launch(void* const* d_in, const int* in_sizes, int n_in,
                              void* d_out, int out_size, void* d_ws, size_t ws_size,
                              hipStream_t stream) {
    const float* x     = (const float*)d_in[0];
    const int*   ei    = (const int*)d_in[1];
    const int*   batch = (const int*)d_in[2];
    const float* W1    = (const float*)d_in[3];
    const float* b1    = (const float*)d_in[4];
    const float* W2    = (const float*)d_in[5];
    const float* b2    = (const float*)d_in[6];
    const float* W3    = (const float*)d_in[7];
    const float* b3    = (const float*)d_in[8];
    float* out = (float*)d_out;

    const int N = N_NODES, E = N_EDGES;
    const int* src = ei;
    const int* dst = ei + E;

    // -------- workspace partition (bytes, 256-aligned) --------
    char* ws = (char*)d_ws;
    float* dinv     = (float*)(ws + 0);          //   400000 B
    int*   degi     = (int*)  (ws + 400128);     //   400000 B (reused as scatter cursor)
    int*   offsets  = (int*)  (ws + 800256);     //   400004 B (N+1 ints)
    int*   csr_src  = (int*)  (ws + 1200384);    //  6400000 B
    float* hbuf     = (float*)(ws + 7600384);    // 25600000 B
    float* aggbuf   = (float*)(ws + 33200384);   // 25600000 B
    float* counts   = (float*)(ws + 58800384);   //     2048 B
    int*   blocksums= (int*)  (ws + 58802432);   //      512 B (98 ints)

    // -------- degree / dinv --------
    hipMemsetAsync(degi, 0, (size_t)N * sizeof(int), stream);
    degree_kernel<<<2048, 256, 0, stream>>>(dst, degi, E);
    dinv_kernel<<<(N + 255) / 256, 256, 0, stream>>>(degi, dinv, N);

    // -------- CSR build: scan + scatter --------
    const int nScanBlocks = (N + 1023) / 1024;   // 98
    scan_block<<<nScanBlocks, 256, 0, stream>>>(degi, offsets, blocksums, N);
    scan_top<<<1, 64, 0, stream>>>(blocksums, nScanBlocks, offsets, N);
    scan_add<<<(N + 255) / 256, 256, 0, stream>>>(offsets, blocksums, N);
    hipMemsetAsync(degi, 0, (size_t)N * sizeof(int), stream);  // reuse as cursor
    scatter_kernel<<<2048, 256, 0, stream>>>(src, dst, offsets, degi, csr_src, E);

    const int gemmGrid   = (N + 63) / 64;
    const int gatherGrid = (N + 3) / 4;

    // ---- layer 1 ----
    gemm64<<<gemmGrid, 256, 0, stream>>>(x, W1, dinv, hbuf, N);
    gather_agg<<<gatherGrid, 256, 0, stream>>>(hbuf, csr_src, offsets, dinv, b1, aggbuf, N, 1);

    // ---- layer 2 ----
    gemm64<<<gemmGrid, 256, 0, stream>>>(aggbuf, W2, dinv, hbuf, N);
    gather_agg<<<gatherGrid, 256, 0, stream>>>(hbuf, csr_src, offsets, dinv, b2, aggbuf, N, 1);

    // ---- layer 3 ----
    gemm64<<<gemmGrid, 256, 0, stream>>>(aggbuf, W3, dinv, hbuf, N);
    gather_agg<<<gatherGrid, 256, 0, stream>>>(hbuf, csr_src, offsets, dinv, b3, aggbuf, N, 0);

    // ---- global mean pool ----
    hipMemsetAsync(out, 0, (size_t)NGRAPH * FDIM * sizeof(float), stream);
    hipMemsetAsync(counts, 0, (size_t)NGRAPH * sizeof(float), stream);
    pool_kernel<<<(N * 64 + 255) / 256, 256, 0, stream>>>(aggbuf, batch, out, counts, N);
    divide_kernel<<<(NGRAPH * FDIM + 255) / 256, 256, 0, stream>>>(out, counts, NGRAPH * FDIM);
}

// Round 3
// 537.937 us; speedup vs baseline: 2.7811x; 1.2881x over previous
//
#include <hip/hip_runtime.h>

#define N_NODES 100000
#define N_EDGES 1600000
#define FDIM 64
#define NGRAPH 512

// ================= degree (int) =================
__global__ void degree_kernel(const int* __restrict__ dst, int* __restrict__ deg, int E) {
    int i = blockIdx.x * blockDim.x + threadIdx.x;
    int stride = gridDim.x * blockDim.x;
    for (; i < E; i += stride) atomicAdd(&deg[dst[i]], 1);
}

__global__ void dinv_kernel(const int* __restrict__ deg, float* __restrict__ dinv, int n) {
    int i = blockIdx.x * blockDim.x + threadIdx.x;
    if (i < n) dinv[i] = rsqrtf((float)deg[i] + 1.0f);  // +1 = self loop
}

// ================= 3-kernel exclusive scan over deg -> offsets =================
__global__ void scan_block(const int* __restrict__ deg, int* __restrict__ excl,
                           int* __restrict__ blocksums, int n) {
    __shared__ int lds[256];
    int t = threadIdx.x;
    int base = blockIdx.x * 1024 + t * 4;
    int v0 = (base     < n) ? deg[base]     : 0;
    int v1 = (base + 1 < n) ? deg[base + 1] : 0;
    int v2 = (base + 2 < n) ? deg[base + 2] : 0;
    int v3 = (base + 3 < n) ? deg[base + 3] : 0;
    int s = v0 + v1 + v2 + v3;
    lds[t] = s;
    __syncthreads();
    for (int off = 1; off < 256; off <<= 1) {
        int x = (t >= off) ? lds[t - off] : 0;
        __syncthreads();
        lds[t] += x;
        __syncthreads();
    }
    int thrExcl = lds[t] - s;
    if (t == 255) blocksums[blockIdx.x] = lds[255];
    if (base     < n) excl[base]     = thrExcl;
    if (base + 1 < n) excl[base + 1] = thrExcl + v0;
    if (base + 2 < n) excl[base + 2] = thrExcl + v0 + v1;
    if (base + 3 < n) excl[base + 3] = thrExcl + v0 + v1 + v2;
}

__global__ void scan_top(int* __restrict__ blocksums, int nb, int* __restrict__ offsets, int n) {
    if (threadIdx.x == 0 && blockIdx.x == 0) {
        int run = 0;
        for (int i = 0; i < nb; ++i) { int v = blocksums[i]; blocksums[i] = run; run += v; }
        offsets[n] = run;  // == E
    }
}

__global__ void scan_add(int* __restrict__ offsets, const int* __restrict__ blocksums, int n) {
    int i = blockIdx.x * blockDim.x + threadIdx.x;
    if (i < n) offsets[i] += blocksums[i >> 10];
}

// ================= CSR scatter =================
__global__ void scatter_kernel(const int* __restrict__ src, const int* __restrict__ dst,
                               const int* __restrict__ offsets, int* __restrict__ cursor,
                               int* __restrict__ csr_src, int E) {
    int i = blockIdx.x * blockDim.x + threadIdx.x;
    int stride = gridDim.x * blockDim.x;
    for (; i < E; i += stride) {
        int d = dst[i];
        int pos = offsets[d] + atomicAdd(&cursor[d], 1);
        csr_src[pos] = src[i];
    }
}

// ================= fp32 GEMM: Hs = (X @ W) * dinv[row] =================
__global__ __launch_bounds__(256) void gemm64(const float* __restrict__ X,
                                              const float* __restrict__ W,
                                              const float* __restrict__ dinv,
                                              float* __restrict__ Hout, int n) {
    __shared__ float Ws[64 * 64];
    __shared__ float Xs[64 * 65];  // Xs[k][row]
    int t = threadIdx.x;
    int r0 = blockIdx.x * 64;

    #pragma unroll
    for (int k = 0; k < 16; ++k) Ws[t + k * 256] = W[t + k * 256];

    #pragma unroll
    for (int k = 0; k < 16; ++k) {
        int idx = t + k * 256;
        int row = idx >> 6, col = idx & 63;
        float v = (r0 + row < n) ? X[(size_t)(r0 + row) * FDIM + col] : 0.0f;
        Xs[col * 65 + row] = v;
    }
    __syncthreads();

    int row = t & 63;
    int cg  = (t >> 6) * 16;
    float acc[16];
    #pragma unroll
    for (int j = 0; j < 16; ++j) acc[j] = 0.0f;

    for (int k = 0; k < 64; ++k) {
        float xv = Xs[k * 65 + row];
        #pragma unroll
        for (int j = 0; j < 16; ++j) acc[j] += xv * Ws[k * 64 + cg + j];
    }

    if (r0 + row < n) {
        float sc = dinv[r0 + row];
        float* o = &Hout[(size_t)(r0 + row) * FDIM + cg];
        #pragma unroll
        for (int j = 0; j < 16; ++j) o[j] = acc[j] * sc;
    }
}

// ================= gather aggregation (fused self-loop + bias + relu) =================
__global__ __launch_bounds__(256) void gather_agg(const float* __restrict__ hs,
                                                  const int* __restrict__ csr_src,
                                                  const int* __restrict__ offsets,
                                                  const float* __restrict__ dinv,
                                                  const float* __restrict__ bias,
                                                  float* __restrict__ outb,
                                                  int n, int do_relu) {
    int node = blockIdx.x * 4 + (threadIdx.x >> 6);
    int lane = threadIdx.x & 63;
    if (node >= n) return;
    int beg = offsets[node], end = offsets[node + 1];
    float acc = 0.0f;
    int k = beg;
    for (; k + 3 < end; k += 4) {
        int s0 = csr_src[k], s1 = csr_src[k + 1], s2 = csr_src[k + 2], s3 = csr_src[k + 3];
        float a0 = hs[(size_t)s0 * FDIM + lane];
        float a1 = hs[(size_t)s1 * FDIM + lane];
        float a2 = hs[(size_t)s2 * FDIM + lane];
        float a3 = hs[(size_t)s3 * FDIM + lane];
        acc += a0 + a1 + a2 + a3;
    }
    for (; k < end; ++k) acc += hs[(size_t)csr_src[k] * FDIM + lane];

    float dd = dinv[node];
    float v = dd * (acc + hs[(size_t)node * FDIM + lane]) + bias[lane];
    if (do_relu) v = fmaxf(v, 0.0f);
    outb[(size_t)node * FDIM + lane] = v;
}

// ================= pooling (batch is sorted -> segmented reduction) =================
// one thread per graph id: binary-search lower bound of g in batch
__global__ void gstart_kernel(const int* __restrict__ batch, int* __restrict__ gstart, int n) {
    int g = blockIdx.x * blockDim.x + threadIdx.x;
    if (g > NGRAPH) return;
    if (g == NGRAPH) { gstart[NGRAPH] = n; return; }
    int lo = 0, hi = n;
    while (lo < hi) {
        int mid = (lo + hi) >> 1;
        if (batch[mid] < g) lo = mid + 1; else hi = mid;
    }
    gstart[g] = lo;
}

// one block (4 waves) per graph; lane = feature; no atomics
__global__ __launch_bounds__(256) void pool2(const float* __restrict__ h,
                                             const int* __restrict__ gstart,
                                             float* __restrict__ out) {
    __shared__ float red[4][64];
    int g = blockIdx.x;
    int beg = gstart[g], end = gstart[g + 1];
    int w = threadIdx.x >> 6, lane = threadIdx.x & 63;
    float acc = 0.0f;
    for (int i = beg + w; i < end; i += 4)
        acc += h[(size_t)i * FDIM + lane];
    red[w][lane] = acc;
    __syncthreads();
    if (w == 0) {
        float tot = red[0][lane] + red[1][lane] + red[2][lane] + red[3][lane];
        float cnt = (float)(end - beg);
        out[(size_t)g * FDIM + lane] = tot / fmaxf(cnt, 1.0f);
    }
}

extern "C" void kernel_launch(void* const* d_in, const int* in_sizes, int n_in,
                              void* d_out, int out_size, void* d_ws, size_t ws_size,
                              hipStream_t stream) {
    const float* x     = (const float*)d_in[0];
    const int*   ei    = (const int*)d_in[1];
    const int*   batch = (const int*)d_in[2];
    const float* W1    = (const float*)d_in[3];
    const float* b1    = (const float*)d_in[4];
    const float* W2    = (const float*)d_in[5];
    const float* b2    = (const float*)d_in[6];
    const float* W3    = (const float*)d_in[7];
    const float* b3    = (const float*)d_in[8];
    float* out = (float*)d_out;

    const int N = N_NODES, E = N_EDGES;
    const int* src = ei;
    const int* dst = ei + E;

    // -------- workspace partition (bytes, 256-aligned) --------
    char* ws = (char*)d_ws;
    float* dinv     = (float*)(ws + 0);          //   400000 B
    int*   degi     = (int*)  (ws + 400128);     //   400000 B (reused as scatter cursor)
    int*   offsets  = (int*)  (ws + 800256);     //   400004 B (N+1 ints)
    int*   csr_src  = (int*)  (ws + 1200384);    //  6400000 B
    float* hbuf     = (float*)(ws + 7600384);    // 25600000 B
    float* aggbuf   = (float*)(ws + 33200384);   // 25600000 B
    int*   gstart   = (int*)  (ws + 58800384);   //     2052 B (G+1 ints)
    int*   blocksums= (int*)  (ws + 58803456);   //      512 B (98 ints)

    // -------- degree / dinv --------
    hipMemsetAsync(degi, 0, (size_t)N * sizeof(int), stream);
    degree_kernel<<<2048, 256, 0, stream>>>(dst, degi, E);
    dinv_kernel<<<(N + 255) / 256, 256, 0, stream>>>(degi, dinv, N);

    // -------- CSR build: scan + scatter --------
    const int nScanBlocks = (N + 1023) / 1024;   // 98
    scan_block<<<nScanBlocks, 256, 0, stream>>>(degi, offsets, blocksums, N);
    scan_top<<<1, 64, 0, stream>>>(blocksums, nScanBlocks, offsets, N);
    scan_add<<<(N + 255) / 256, 256, 0, stream>>>(offsets, blocksums, N);
    hipMemsetAsync(degi, 0, (size_t)N * sizeof(int), stream);  // reuse as cursor
    scatter_kernel<<<2048, 256, 0, stream>>>(src, dst, offsets, degi, csr_src, E);

    // -------- graph boundaries (batch sorted) --------
    gstart_kernel<<<3, 256, 0, stream>>>(batch, gstart, N);

    const int gemmGrid   = (N + 63) / 64;
    const int gatherGrid = (N + 3) / 4;

    // ---- layer 1 ----
    gemm64<<<gemmGrid, 256, 0, stream>>>(x, W1, dinv, hbuf, N);
    gather_agg<<<gatherGrid, 256, 0, stream>>>(hbuf, csr_src, offsets, dinv, b1, aggbuf, N, 1);

    // ---- layer 2 ----
    gemm64<<<gemmGrid, 256, 0, stream>>>(aggbuf, W2, dinv, hbuf, N);
    gather_agg<<<gatherGrid, 256, 0, stream>>>(hbuf, csr_src, offsets, dinv, b2, aggbuf, N, 1);

    // ---- layer 3 ----
    gemm64<<<gemmGrid, 256, 0, stream>>>(aggbuf, W3, dinv, hbuf, N);
    gather_agg<<<gatherGrid, 256, 0, stream>>>(hbuf, csr_src, offsets, dinv, b3, aggbuf, N, 0);

    // ---- global mean pool (no atomics) ----
    pool2<<<NGRAPH, 256, 0, stream>>>(aggbuf, gstart, out);
}

// Round 4
// 485.223 us; speedup vs baseline: 3.0832x; 1.1086x over previous
//
#include <hip/hip_runtime.h>

#define N_NODES 100000
#define N_EDGES 1600000
#define FDIM 64
#define NGRAPH 512
#define NB 782          // dst buckets of 128 nodes: ceil(100000/128)
#define NWG 256         // workgroups in hist/bin passes
#define CHUNK 6250      // E / NWG

// ================= degree (int) =================
__global__ void degree_kernel(const int* __restrict__ dst, int* __restrict__ deg, int E) {
    int i = blockIdx.x * blockDim.x + threadIdx.x;
    int stride = gridDim.x * blockDim.x;
    for (; i < E; i += stride) atomicAdd(&deg[dst[i]], 1);
}

__global__ void dinv_kernel(const int* __restrict__ deg, float* __restrict__ dinv, int n) {
    int i = blockIdx.x * blockDim.x + threadIdx.x;
    if (i < n) dinv[i] = rsqrtf((float)deg[i] + 1.0f);  // +1 = self loop
}

// ================= 3-kernel exclusive scan =================
__global__ void scan_block(const int* __restrict__ deg, int* __restrict__ excl,
                           int* __restrict__ blocksums, int n) {
    __shared__ int lds[256];
    int t = threadIdx.x;
    int base = blockIdx.x * 1024 + t * 4;
    int v0 = (base     < n) ? deg[base]     : 0;
    int v1 = (base + 1 < n) ? deg[base + 1] : 0;
    int v2 = (base + 2 < n) ? deg[base + 2] : 0;
    int v3 = (base + 3 < n) ? deg[base + 3] : 0;
    int s = v0 + v1 + v2 + v3;
    lds[t] = s;
    __syncthreads();
    for (int off = 1; off < 256; off <<= 1) {
        int x = (t >= off) ? lds[t - off] : 0;
        __syncthreads();
        lds[t] += x;
        __syncthreads();
    }
    int thrExcl = lds[t] - s;
    if (t == 255) blocksums[blockIdx.x] = lds[255];
    if (base     < n) excl[base]     = thrExcl;
    if (base + 1 < n) excl[base + 1] = thrExcl + v0;
    if (base + 2 < n) excl[base + 2] = thrExcl + v0 + v1;
    if (base + 3 < n) excl[base + 3] = thrExcl + v0 + v1 + v2;
}

__global__ void scan_top(int* __restrict__ blocksums, int nb, int* __restrict__ offsets, int n) {
    if (threadIdx.x == 0 && blockIdx.x == 0) {
        int run = 0;
        for (int i = 0; i < nb; ++i) { int v = blocksums[i]; blocksums[i] = run; run += v; }
        offsets[n] = run;
    }
}

__global__ void scan_add(int* __restrict__ offsets, const int* __restrict__ blocksums, int n) {
    int i = blockIdx.x * blockDim.x + threadIdx.x;
    if (i < n) offsets[i] += blocksums[i >> 10];
}

// ================= pass A: per-wg bucket histogram =================
__global__ __launch_bounds__(256) void hist_kernel(const int* __restrict__ dst,
                                                   int* __restrict__ hist, int E) {
    __shared__ int h[NB];
    int t = threadIdx.x, wg = blockIdx.x;
    for (int i = t; i < NB; i += 256) h[i] = 0;
    __syncthreads();
    int beg = wg * CHUNK, end = min(beg + CHUNK, E);
    for (int i = beg + t; i < end; i += 256) atomicAdd(&h[dst[i] >> 7], 1);
    __syncthreads();
    for (int i = t; i < NB; i += 256) hist[i * NWG + wg] = h[i];
}

// ================= pass B: binned append (LDS cursors, packed 4B edges) =================
__global__ __launch_bounds__(256) void bin_kernel(const int* __restrict__ src,
                                                  const int* __restrict__ dst,
                                                  const int* __restrict__ scannedH,
                                                  int* __restrict__ ebin, int E) {
    __shared__ int base[NB];
    __shared__ int cur[NB];
    int t = threadIdx.x, wg = blockIdx.x;
    for (int i = t; i < NB; i += 256) { base[i] = scannedH[i * NWG + wg]; cur[i] = 0; }
    __syncthreads();
    int beg = wg * CHUNK, end = min(beg + CHUNK, E);
    for (int i = beg + t; i < end; i += 256) {
        int d = dst[i];
        int b = d >> 7;
        int p = base[b] + atomicAdd(&cur[b], 1);
        ebin[p] = ((d & 127) << 17) | src[i];
    }
}

// ================= pass C: per-bucket LDS counting sort -> coalesced CSR =================
__global__ __launch_bounds__(256) void csr_sort_kernel(const int* __restrict__ ebin,
                                                       const int* __restrict__ scannedH,
                                                       const int* __restrict__ offsets,
                                                       int* __restrict__ csr_src, int E) {
    __shared__ int segStart[128];
    __shared__ int cur[128];
    __shared__ int buf[4352];   // max bucket span ~2350 with huge margin
    int t = threadIdx.x, b = blockIdx.x;
    int nbase = b << 7;
    int nodes = min(128, N_NODES - nbase);
    int bstart = scannedH[b * NWG];
    int bend = (b == NB - 1) ? E : scannedH[(b + 1) * NWG];
    if (t < nodes) { segStart[t] = offsets[nbase + t] - bstart; cur[t] = 0; }
    __syncthreads();
    for (int i = bstart + t; i < bend; i += 256) {
        int v = ebin[i];
        int l = v >> 17;
        int s = v & 0x1FFFF;
        int p = segStart[l] + atomicAdd(&cur[l], 1);
        buf[p] = s;
    }
    __syncthreads();
    int span = bend - bstart;
    for (int i = t; i < span; i += 256) csr_src[bstart + i] = buf[i];
}

// ================= fp32 GEMM: Hs = (X @ W) * dinv[row] =================
__global__ __launch_bounds__(256) void gemm64(const float* __restrict__ X,
                                              const float* __restrict__ W,
                                              const float* __restrict__ dinv,
                                              float* __restrict__ Hout, int n) {
    __shared__ float Ws[64 * 64];
    __shared__ float Xs[64 * 65];
    int t = threadIdx.x;
    int r0 = blockIdx.x * 64;

    #pragma unroll
    for (int k = 0; k < 16; ++k) Ws[t + k * 256] = W[t + k * 256];

    #pragma unroll
    for (int k = 0; k < 16; ++k) {
        int idx = t + k * 256;
        int row = idx >> 6, col = idx & 63;
        float v = (r0 + row < n) ? X[(size_t)(r0 + row) * FDIM + col] : 0.0f;
        Xs[col * 65 + row] = v;
    }
    __syncthreads();

    int row = t & 63;
    int cg  = (t >> 6) * 16;
    float acc[16];
    #pragma unroll
    for (int j = 0; j < 16; ++j) acc[j] = 0.0f;

    for (int k = 0; k < 64; ++k) {
        float xv = Xs[k * 65 + row];
        #pragma unroll
        for (int j = 0; j < 16; ++j) acc[j] += xv * Ws[k * 64 + cg + j];
    }

    if (r0 + row < n) {
        float sc = dinv[r0 + row];
        float* o = &Hout[(size_t)(r0 + row) * FDIM + cg];
        #pragma unroll
        for (int j = 0; j < 16; ++j) o[j] = acc[j] * sc;
    }
}

// ================= gather aggregation (fused self-loop + bias + relu) =================
__global__ __launch_bounds__(256) void gather_agg(const float* __restrict__ hs,
                                                  const int* __restrict__ csr_src,
                                                  const int* __restrict__ offsets,
                                                  const float* __restrict__ dinv,
                                                  const float* __restrict__ bias,
                                                  float* __restrict__ outb,
                                                  int n, int do_relu) {
    int node = blockIdx.x * 4 + (threadIdx.x >> 6);
    int lane = threadIdx.x & 63;
    if (node >= n) return;
    int beg = offsets[node], end = offsets[node + 1];
    float acc = 0.0f;
    int k = beg;
    for (; k + 3 < end; k += 4) {
        int s0 = csr_src[k], s1 = csr_src[k + 1], s2 = csr_src[k + 2], s3 = csr_src[k + 3];
        float a0 = hs[(size_t)s0 * FDIM + lane];
        float a1 = hs[(size_t)s1 * FDIM + lane];
        float a2 = hs[(size_t)s2 * FDIM + lane];
        float a3 = hs[(size_t)s3 * FDIM + lane];
        acc += a0 + a1 + a2 + a3;
    }
    for (; k < end; ++k) acc += hs[(size_t)csr_src[k] * FDIM + lane];

    float dd = dinv[node];
    float v = dd * (acc + hs[(size_t)node * FDIM + lane]) + bias[lane];
    if (do_relu) v = fmaxf(v, 0.0f);
    outb[(size_t)node * FDIM + lane] = v;
}

// ================= pooling (batch sorted -> segmented reduction) =================
__global__ void gstart_kernel(const int* __restrict__ batch, int* __restrict__ gstart, int n) {
    int g = blockIdx.x * blockDim.x + threadIdx.x;
    if (g > NGRAPH) return;
    if (g == NGRAPH) { gstart[NGRAPH] = n; return; }
    int lo = 0, hi = n;
    while (lo < hi) {
        int mid = (lo + hi) >> 1;
        if (batch[mid] < g) lo = mid + 1; else hi = mid;
    }
    gstart[g] = lo;
}

__global__ __launch_bounds__(256) void pool2(const float* __restrict__ h,
                                             const int* __restrict__ gstart,
                                             float* __restrict__ out) {
    __shared__ float red[4][64];
    int g = blockIdx.x;
    int beg = gstart[g], end = gstart[g + 1];
    int w = threadIdx.x >> 6, lane = threadIdx.x & 63;
    float acc = 0.0f;
    for (int i = beg + w; i < end; i += 4)
        acc += h[(size_t)i * FDIM + lane];
    red[w][lane] = acc;
    __syncthreads();
    if (w == 0) {
        float tot = red[0][lane] + red[1][lane] + red[2][lane] + red[3][lane];
        float cnt = (float)(end - beg);
        out[(size_t)g * FDIM + lane] = tot / fmaxf(cnt, 1.0f);
    }
}

extern "C" void kernel_launch(void* const* d_in, const int* in_sizes, int n_in,
                              void* d_out, int out_size, void* d_ws, size_t ws_size,
                              hipStream_t stream) {
    const float* x     = (const float*)d_in[0];
    const int*   ei    = (const int*)d_in[1];
    const int*   batch = (const int*)d_in[2];
    const float* W1    = (const float*)d_in[3];
    const float* b1    = (const float*)d_in[4];
    const float* W2    = (const float*)d_in[5];
    const float* b2    = (const float*)d_in[6];
    const float* W3    = (const float*)d_in[7];
    const float* b3    = (const float*)d_in[8];
    float* out = (float*)d_out;

    const int N = N_NODES, E = N_EDGES;
    const int* src = ei;
    const int* dst = ei + E;

    // -------- workspace partition (bytes, 256-aligned) --------
    char* ws = (char*)d_ws;
    float* dinv      = (float*)(ws + 0);          //   400000 B
    int*   degi      = (int*)  (ws + 400128);     //   400000 B
    int*   offsets   = (int*)  (ws + 800256);     //   400004 B (N+1)
    int*   csr_src   = (int*)  (ws + 1200384);    //  6400000 B
    float* hbuf      = (float*)(ws + 7600384);    // 25600000 B
    float* aggbuf    = (float*)(ws + 33200384);   // 25600000 B
    int*   gstart    = (int*)  (ws + 58800384);   //     2052 B
    int*   blocksumsN= (int*)  (ws + 58803456);   //      512 B (98 ints)
    // aliases into dead regions (used only before gemm1/gather1):
    int*   scannedH  = (int*)  (ws + 7600384);            // NB*NWG+1 ints (801 KB) in hbuf
    int*   blocksumsH= (int*)  (ws + 7600384 + 1000448);  // 196 ints, in hbuf
    int*   ebin      = (int*)  (ws + 33200384);           // E ints (6.4 MB) in aggbuf

    // -------- degree / dinv / node offsets --------
    hipMemsetAsync(degi, 0, (size_t)N * sizeof(int), stream);
    degree_kernel<<<2048, 256, 0, stream>>>(dst, degi, E);
    dinv_kernel<<<(N + 255) / 256, 256, 0, stream>>>(degi, dinv, N);

    const int nScanN = (N + 1023) / 1024;  // 98
    scan_block<<<nScanN, 256, 0, stream>>>(degi, offsets, blocksumsN, N);
    scan_top<<<1, 64, 0, stream>>>(blocksumsN, nScanN, offsets, N);
    scan_add<<<(N + 255) / 256, 256, 0, stream>>>(offsets, blocksumsN, N);

    // -------- bucketed counting sort -> CSR --------
    hist_kernel<<<NWG, 256, 0, stream>>>(dst, scannedH, E);
    const int nH = NB * NWG;               // 200192
    const int nScanH = (nH + 1023) / 1024; // 196
    scan_block<<<nScanH, 256, 0, stream>>>(scannedH, scannedH, blocksumsH, nH);
    scan_top<<<1, 64, 0, stream>>>(blocksumsH, nScanH, scannedH, nH);
    scan_add<<<(nH + 255) / 256, 256, 0, stream>>>(scannedH, blocksumsH, nH);
    bin_kernel<<<NWG, 256, 0, stream>>>(src, dst, scannedH, ebin, E);
    csr_sort_kernel<<<NB, 256, 0, stream>>>(ebin, scannedH, offsets, csr_src, E);

    // -------- graph boundaries (batch sorted) --------
    gstart_kernel<<<3, 256, 0, stream>>>(batch, gstart, N);

    const int gemmGrid   = (N + 63) / 64;
    const int gatherGrid = (N + 3) / 4;

    // ---- layer 1 ----
    gemm64<<<gemmGrid, 256, 0, stream>>>(x, W1, dinv, hbuf, N);
    gather_agg<<<gatherGrid, 256, 0, stream>>>(hbuf, csr_src, offsets, dinv, b1, aggbuf, N, 1);

    // ---- layer 2 ----
    gemm64<<<gemmGrid, 256, 0, stream>>>(aggbuf, W2, dinv, hbuf, N);
    gather_agg<<<gatherGrid, 256, 0, stream>>>(hbuf, csr_src, offsets, dinv, b2, aggbuf, N, 1);

    // ---- layer 3 ----
    gemm64<<<gemmGrid, 256, 0, stream>>>(aggbuf, W3, dinv, hbuf, N);
    gather_agg<<<gatherGrid, 256, 0, stream>>>(hbuf, csr_src, offsets, dinv, b3, aggbuf, N, 0);

    // ---- global mean pool (no atomics) ----
    pool2<<<NGRAPH, 256, 0, stream>>>(aggbuf, gstart, out);
}